// Round 1
// 141.221 us; speedup vs baseline: 1.0432x; 1.0432x over previous
//
#include <hip/hip_runtime.h>
#include <stdint.h>

typedef unsigned short u16;
typedef unsigned int   u32;
typedef __bf16 bf16_t;
typedef bf16_t bf16x8 __attribute__((ext_vector_type(8)));
typedef bf16_t bf16x2 __attribute__((ext_vector_type(2)));
typedef float  f32x2  __attribute__((ext_vector_type(2)));
typedef float  f32x4  __attribute__((ext_vector_type(4)));

// bs=8, H=8 -> bH=64 ; T=1024 ; ch=64 ; classes 0..7, null token idx 8.
// Math: k-bias is row-constant over surviving keys -> drops out of softmax;
// v-bias passes through softmax as exactly +v_bias -> added in epilogue;
// counter==2 -> out = 0.5*(A_null + A_class).  No-max softmax: logits in
// exp2-domain have sigma~1.44 (scale folded into Q), so raw exp2 is safe.
//
// R10: staging redundancy was the wall (16 qt-blocks per bh each re-loaded,
// re-converted and re-ds_wrote the same K/V; VALU 39%, 5.37M LDS-conflict
// cycles).  Now a prep pass converts K/V to bf16 ONCE into per-(bh,kt)
// contiguous 16KB "LDS images", XOR-swizzled (elem ^= (row&7)<<3) so all
// ds_read_b128 in attn are bank-uniform.  Attn stages via
// global_load_lds_dwordx4 (pure DMA, no VALU) into a 2x16KB double buffer:
// loads for tile kt+1 issue right after the barrier and drain at the NEXT
// barrier -> one full compute phase of prefetch distance.
#define QSCALE 0.18033688011112042f   /* 0.125 * log2(e) */

__device__ __forceinline__ u32 pkbf(float a, float b) {
  f32x2 x = {a, b};
  bf16x2 y = __builtin_convertvector(x, bf16x2);   // RNE; v_cvt_pk_bf16_f32
  union { bf16x2 v; u32 u; } c; c.v = y; return c.u;
}

// raw v_exp_f32: libm exp2f (no fast-math) lowers to a multi-instruction
// denormal-fixup expansion; raw instruction is exact for our exponent range.
__device__ __forceinline__ float fexp2(float x) {
#if __has_builtin(__builtin_amdgcn_exp2f)
  return __builtin_amdgcn_exp2f(x);
#else
  float r;
  asm("v_exp_f32 %0, %1\n\ts_nop 0" : "=v"(r) : "v"(x));
  return r;
#endif
}

// async global->LDS, 16B per lane.  HW dest = wave-uniform base + lane*16,
// which our linear tid*16 mapping satisfies exactly.
__device__ __forceinline__ void gload_lds16(const void* g, void* l) {
  __builtin_amdgcn_global_load_lds(
      (const __attribute__((address_space(1))) void*)g,
      (__attribute__((address_space(3))) void*)l, 16, 0, 0);
}

// ---- kernel 1: prep ---------------------------------------------------------
// blocks 0..1023  : (bh,kt) -> 16KB tile image: [K 8KB | V 8KB], bf16,
//                   XOR-swizzled: elem offset ^= (row&7)<<3 within each row.
//                   K rows = key s (64 elems d);  V rows = d (64 cols
//                   col' = sigma(s) = (s&15)*4 + (s>>4)).
// blocks 1024..1455: tok[c][j] = sum_i W_cls[j,i]*embed[c,i], one wave per
//                   (c,j) (9*192 = 1728 waves = 432 blocks).
__global__ __launch_bounds__(256)
void prep_kernel(const float* __restrict__ qkv,
                 const float* __restrict__ W, const float* __restrict__ E,
                 float* __restrict__ tok, u16* __restrict__ tiles) {
  const int B = blockIdx.x;
  const int tid = threadIdx.x;
  if (B >= 1024) {
    const int gw = (B - 1024) * 4 + (tid >> 6);
    const int lane = tid & 63;
    if (gw < 1728) {
      const int c = gw / 192, j = gw - c * 192;
      const f32x4* w4 = (const f32x4*)(W + (size_t)j * 512 + lane * 8);
      const f32x4* e4 = (const f32x4*)(E + (size_t)c * 512 + lane * 8);
      float acc = 0.f;
#pragma unroll
      for (int i = 0; i < 2; ++i) {
        f32x4 w = w4[i], e = e4[i];
        acc += w.x * e.x + w.y * e.y + w.z * e.z + w.w * e.w;
      }
#pragma unroll
      for (int off = 32; off; off >>= 1) acc += __shfl_xor(acc, off, 64);
      if (lane == 0) tok[c * 192 + j] = acc;
    }
    return;
  }
  const int bh = B >> 4, kt = B & 15;
  const int s0 = kt * 64;
  const float* qg = qkv + (size_t)bh * 192 * 1024;
  u16* img = tiles + (size_t)B * 8192;          // 16 KiB per (bh,kt)
  // K half: thread -> (s = tid&63, g = tid>>6), 16 d's, d-strided loads.
  {
    const int s = tid & 63, g = tid >> 6;
    const float* kb = qg + (size_t)(64 + g * 16) * 1024 + s0 + s;
    float kf[16];
#pragma unroll
    for (int i = 0; i < 16; ++i) kf[i] = kb[(size_t)i * 1024];
    u32 kp[8];
#pragma unroll
    for (int j2 = 0; j2 < 8; ++j2) kp[j2] = pkbf(kf[2 * j2], kf[2 * j2 + 1]);
    const int xr = (s & 7) << 3;
    *(uint4*)&img[s * 64 + ((g * 16)     ^ xr)] = make_uint4(kp[0], kp[1], kp[2], kp[3]);
    *(uint4*)&img[s * 64 + ((g * 16 + 8) ^ xr)] = make_uint4(kp[4], kp[5], kp[6], kp[7]);
  }
  // V half: thread -> (lV = tid&15, dg = tid>>4), 4 d's, sigma-grouped s.
  {
    const int lV = tid & 15, dg = tid >> 4;
    const float* vb = qg + (size_t)(128 + dg * 4) * 1024 + s0 + lV;
#pragma unroll
    for (int i = 0; i < 4; ++i) {
      float v0 = vb[(size_t)i * 1024 +  0];
      float v1 = vb[(size_t)i * 1024 + 16];
      float v2 = vb[(size_t)i * 1024 + 32];
      float v3 = vb[(size_t)i * 1024 + 48];
      const int d = dg * 4 + i;
      *(uint2*)&img[4096 + d * 64 + ((lV * 4) ^ ((d & 7) << 3))] =
          make_uint2(pkbf(v0, v1), pkbf(v2, v3));
    }
  }
}

// ---- kernel 2: two-stream flash attention ----------------------------------
__global__ __launch_bounds__(256, 3)
void attn_kernel(const float* __restrict__ qkv, const int* __restrict__ seg,
                 const float* __restrict__ tok, const u16* __restrict__ tiles,
                 float* __restrict__ out) {
  // [buf0 16KB | buf1 16KB | P 4 waves x 4KB] = 49152 B -> 3 blocks/CU.
  __shared__ __align__(16) u16 smem[24576];

  const int L  = blockIdx.x;
  const int bh = (L & 7) * 8 + ((L >> 3) & 7);   // same bh -> same XCD residue
  const int qt = L >> 6;                          // 0..15
  const int b  = bh >> 3;
  const int tid = threadIdx.x, wave = tid >> 6, lane = tid & 63;
  const int quad = lane >> 4, l16 = lane & 15;
  u16* Pw = smem + 16384 + wave * 2048;           // [2 streams][16][64]

  const float* qg   = qkv + (size_t)bh * 192 * 1024;
  const int*   segb = seg + b * 1024;
  const u16*   tbh  = tiles + (size_t)bh * (16 * 8192);

  // --- per-lane segment info -------------------------------------------------
  const int tq = qt * 64 + wave * 16 + l16;
  const int mycls = segb[tq];
  int sq[4];
#pragma unroll
  for (int r = 0; r < 4; ++r) sq[r] = segb[qt * 64 + wave * 16 + quad * 4 + r];

  // --- Q fragments (A-layout: m=l16=query, k=d=kc*32+quad*8+j) --------------
  const float* tn = tok + 8 * 192;
  const float* tc = tok + mycls * 192;
  union { u32 w[4]; bf16x8 v; } q0f[2], qbf[2];
#pragma unroll
  for (int kc = 0; kc < 2; ++kc)
#pragma unroll
    for (int jj = 0; jj < 4; ++jj) {
      int d = kc * 32 + quad * 8 + jj * 2;
      float a0 = qg[(size_t)d * 1024 + tq];
      float a1 = qg[(size_t)(d + 1) * 1024 + tq];
      q0f[kc].w[jj] = pkbf((a0 + tn[d]) * QSCALE, (a1 + tn[d + 1]) * QSCALE);
      qbf[kc].w[jj] = pkbf((a0 + tc[d]) * QSCALE, (a1 + tc[d + 1]) * QSCALE);
    }

  f32x4 O0[4], Ob[4];
#pragma unroll
  for (int dt = 0; dt < 4; ++dt) {
    O0[dt] = (f32x4){0.f, 0.f, 0.f, 0.f};
    Ob[dt] = (f32x4){0.f, 0.f, 0.f, 0.f};
  }
  float rs0[4] = {0.f, 0.f, 0.f, 0.f}, rsb[4] = {0.f, 0.f, 0.f, 0.f};

  // prologue: DMA tile 0 into buf0
  {
    const char* src = (const char*)tbh + tid * 16;
    char* dst = (char*)smem + tid * 16;
#pragma unroll
    for (int i = 0; i < 4; ++i) gload_lds16(src + i * 4096, dst + i * 4096);
  }

  const int xq = (l16 & 7) << 3;   // XOR for all row&7 == l16&7 accesses

  // ---- key-tile loop (16 x 64 keys) ----------------------------------------
#pragma unroll 2
  for (int kt = 0; kt < 16; ++kt) {
    const int s0 = kt * 64;
    __syncthreads();            // drains our DMA (vmcnt 0) + frees other buf
    if (kt + 1 < 16) {          // prefetch next tile across the whole compute
      const char* src = (const char*)tbh + (size_t)(kt + 1) * 16384 + tid * 16;
      char* dst = (char*)smem + ((kt + 1) & 1) * 16384 + tid * 16;
#pragma unroll
      for (int i = 0; i < 4; ++i) gload_lds16(src + i * 4096, dst + i * 4096);
    }
    int sk[4];
#pragma unroll
    for (int n4 = 0; n4 < 4; ++n4) sk[n4] = segb[s0 + n4 * 16 + l16];

    const u16* ktr = smem + (kt & 1) * 8192;   // K image [s][64]
    const u16* vls = ktr + 4096;               // V image [d][64]

    // ---- S = Q K^T, both streams (B-frag: n=key=n4*16+l16, k=d) -----------
    f32x4 S0[4], Sb[4];
#pragma unroll
    for (int n4 = 0; n4 < 4; ++n4) {
      const int scol = n4 * 16 + l16;          // scol&7 == l16&7 -> xq
      f32x4 a0 = {0.f, 0.f, 0.f, 0.f}, ab = {0.f, 0.f, 0.f, 0.f};
#pragma unroll
      for (int kc = 0; kc < 2; ++kc) {
        bf16x8 kfr = *(const bf16x8*)&ktr[scol * 64 + ((kc * 32 + quad * 8) ^ xq)];
        a0 = __builtin_amdgcn_mfma_f32_16x16x32_bf16(q0f[kc].v, kfr, a0, 0, 0, 0);
        ab = __builtin_amdgcn_mfma_f32_16x16x32_bf16(qbf[kc].v, kfr, ab, 0, 0, 0);
      }
      S0[n4] = a0; Sb[n4] = ab;
    }

    // ---- no-max softmax: raw exp2, per-lane partial row sums --------------
#pragma unroll
    for (int r = 0; r < 4; ++r) {
      const int row = quad * 4 + r;
      const int po = row * 64 + ((l16 * 4) ^ ((row & 7) << 3));
      float p0[4], pb[4];
#pragma unroll
      for (int n4 = 0; n4 < 4; ++n4) {
        p0[n4] = fexp2(S0[n4][r]);
        pb[n4] = (sk[n4] == sq[r]) ? fexp2(Sb[n4][r]) : 0.f;
      }
      rs0[r] += (p0[0] + p0[1]) + (p0[2] + p0[3]);
      rsb[r] += (pb[0] + pb[1]) + (pb[2] + pb[3]);
      // P at col' = sigma(s) = l16*4 + n4  -> one b64 per stream
      *(uint2*)&Pw[po]        = make_uint2(pkbf(p0[0], p0[1]), pkbf(p0[2], p0[3]));
      *(uint2*)&Pw[1024 + po] = make_uint2(pkbf(pb[0], pb[1]), pkbf(pb[2], pb[3]));
    }
    asm volatile("s_waitcnt lgkmcnt(0)" ::: "memory");  // wave-private P RAW

    // ---- O += P V  (A=P[m=q][k=col'], B=V[k=col'][n=d]) -------------------
#pragma unroll
    for (int kc = 0; kc < 2; ++kc) {
      const int co = (kc * 32 + quad * 8) ^ xq;
      bf16x8 pf0 = *(const bf16x8*)&Pw[l16 * 64 + co];
      bf16x8 pfb = *(const bf16x8*)&Pw[1024 + l16 * 64 + co];
#pragma unroll
      for (int dt = 0; dt < 4; ++dt) {
        bf16x8 vfr = *(const bf16x8*)&vls[(dt * 16 + l16) * 64 + co];
        O0[dt] = __builtin_amdgcn_mfma_f32_16x16x32_bf16(pf0, vfr, O0[dt], 0, 0, 0);
        Ob[dt] = __builtin_amdgcn_mfma_f32_16x16x32_bf16(pfb, vfr, Ob[dt], 0, 0, 0);
      }
    }
  }

  // ---- final row-sum reduction (within 16-lane row groups) -----------------
#pragma unroll
  for (int r = 0; r < 4; ++r)
#pragma unroll
    for (int off = 1; off < 16; off <<= 1) {
      rs0[r] += __shfl_xor(rs0[r], off, 64);
      rsb[r] += __shfl_xor(rsb[r], off, 64);
    }
  float inv0[4], invb[4];
#pragma unroll
  for (int r = 0; r < 4; ++r) {
    inv0[r] = (rs0[r] > 0.f) ? 1.f / rs0[r] : 0.f;
    invb[r] = (rsb[r] > 0.f) ? 1.f / rsb[r] : 0.f;
  }

  // ---- epilogue: divide, add analytic v-biases, transpose via LDS, store ---
  __syncthreads();                        // all LDS tile reads done
  float* fbuf = (float*)smem;             // [64 d][65] fp32 (16640 B)
  const float* tvn = tok + 8 * 192 + 128;
#pragma unroll
  for (int dt = 0; dt < 4; ++dt) {
    const int d = dt * 16 + l16;
    const float bn = tvn[d];
#pragma unroll
    for (int r = 0; r < 4; ++r) {
      float bc = tok[sq[r] * 192 + 128 + d];
      float vA = O0[dt][r] * inv0[r] + bn;
      float vB = Ob[dt][r] * invb[r] + bc;
      fbuf[d * 65 + wave * 16 + quad * 4 + r] = 0.5f * (vA + vB);
    }
  }
  __syncthreads();
  {
    // out flat = d*65536 + bh*1024 + t   (stacked (ch, bH, T) row-major)
    const size_t obase = (size_t)bh * 1024 + qt * 64;
    for (int i = tid; i < 4096; i += 256) {
      int d = i >> 6, t = i & 63;
      out[(size_t)d * 65536 + obase + t] = fbuf[d * 65 + t];
    }
  }
}

// ---- host ------------------------------------------------------------------
extern "C" void kernel_launch(void* const* d_in, const int* in_sizes, int n_in,
                              void* d_out, int out_size, void* d_ws, size_t ws_size,
                              hipStream_t stream) {
  (void)in_sizes; (void)n_in; (void)out_size; (void)ws_size;
  const float* qkv   = (const float*)d_in[0];
  const int*   amask = (const int*)d_in[1];
  const float* emb   = (const float*)d_in[2];
  const float* wcls  = (const float*)d_in[3];
  float* tok   = (float*)d_ws;                       // 1728 floats
  u16*   tiles = (u16*)((char*)d_ws + 8192);         // 16 MiB of tile images
  float* out = (float*)d_out;

  hipLaunchKernelGGL(prep_kernel, dim3(1456), dim3(256), 0, stream,
                     qkv, wcls, emb, tok, tiles);
  hipLaunchKernelGGL(attn_kernel, dim3(1024), dim3(256), 0, stream,
                     qkv, amask, tok, tiles, out);
}

// Round 2
// 137.292 us; speedup vs baseline: 1.0730x; 1.0286x over previous
//
#include <hip/hip_runtime.h>
#include <stdint.h>

typedef unsigned short u16;
typedef unsigned int   u32;
typedef __bf16 bf16_t;
typedef bf16_t bf16x8 __attribute__((ext_vector_type(8)));
typedef bf16_t bf16x2 __attribute__((ext_vector_type(2)));
typedef float  f32x2  __attribute__((ext_vector_type(2)));
typedef float  f32x4  __attribute__((ext_vector_type(4)));

// bs=8, H=8 -> bH=64 ; T=1024 ; ch=64 ; classes 0..7, null token idx 8.
// Math: k-bias is row-constant over surviving keys -> drops out of softmax;
// v-bias passes through softmax as exactly +v_bias -> added in epilogue;
// counter==2 -> out = 0.5*(A_null + A_class).  No-max softmax: logits in
// exp2-domain have sigma~1.44 (scale folded into Q), so raw exp2 is safe.
//
// R11: swapped-operand QK^T.  S^T = mfma(K, Q) puts each lane's 16 P values
// on its OWN query row (C col = lane&15 = query), which is exactly the PV
// A-frag lane.  With V column order sigma(s)= (n4>>1)*32 + quad*8 + (n4&1)*4
// + r  (s = n4*16+quad*4+r), the 16 keys a lane holds are exactly the 16
// k-slots its two A-frags need: P never touches LDS, no cross-lane moves,
// no lgkmcnt stall.  P LDS buffer deleted -> LDS 32 KB -> 4-5 blocks/CU.
// Denominator: per-lane accumulation + shfl_xor(16,32) once at the end.
#define QSCALE 0.18033688011112042f   /* 0.125 * log2(e) */

__device__ __forceinline__ u32 pkbf(float a, float b) {
  f32x2 x = {a, b};
  bf16x2 y = __builtin_convertvector(x, bf16x2);   // RNE; v_cvt_pk_bf16_f32
  union { bf16x2 v; u32 u; } c; c.v = y; return c.u;
}

// raw v_exp_f32: libm exp2f (no fast-math) lowers to a multi-instruction
// denormal-fixup expansion; raw instruction is exact for our exponent range.
__device__ __forceinline__ float fexp2(float x) {
#if __has_builtin(__builtin_amdgcn_exp2f)
  return __builtin_amdgcn_exp2f(x);
#else
  float r;
  asm("v_exp_f32 %0, %1\n\ts_nop 0" : "=v"(r) : "v"(x));
  return r;
#endif
}

// async global->LDS, 16B per lane.  HW dest = wave-uniform base + lane*16,
// which our linear tid*16 mapping satisfies exactly.
__device__ __forceinline__ void gload_lds16(const void* g, void* l) {
  __builtin_amdgcn_global_load_lds(
      (const __attribute__((address_space(1))) void*)g,
      (__attribute__((address_space(3))) void*)l, 16, 0, 0);
}

// ---- kernel 1: prep ---------------------------------------------------------
// blocks 0..1023  : (bh,kt) -> 16KB tile image: [K 8KB | V 8KB], bf16,
//                   XOR-swizzled: elem offset ^= (row&7)<<3 within each row.
//                   K rows = key s (64 elems d);  V rows = d (64 cols,
//                   col' = sigma(s) as derived above).
// blocks 1024..1455: tok[c][j] = sum_i W_cls[j,i]*embed[c,i], one wave per
//                   (c,j) (9*192 = 1728 waves = 432 blocks).
__global__ __launch_bounds__(256)
void prep_kernel(const float* __restrict__ qkv,
                 const float* __restrict__ W, const float* __restrict__ E,
                 float* __restrict__ tok, u16* __restrict__ tiles) {
  const int B = blockIdx.x;
  const int tid = threadIdx.x;
  if (B >= 1024) {
    const int gw = (B - 1024) * 4 + (tid >> 6);
    const int lane = tid & 63;
    if (gw < 1728) {
      const int c = gw / 192, j = gw - c * 192;
      const f32x4* w4 = (const f32x4*)(W + (size_t)j * 512 + lane * 8);
      const f32x4* e4 = (const f32x4*)(E + (size_t)c * 512 + lane * 8);
      float acc = 0.f;
#pragma unroll
      for (int i = 0; i < 2; ++i) {
        f32x4 w = w4[i], e = e4[i];
        acc += w.x * e.x + w.y * e.y + w.z * e.z + w.w * e.w;
      }
#pragma unroll
      for (int off = 32; off; off >>= 1) acc += __shfl_xor(acc, off, 64);
      if (lane == 0) tok[c * 192 + j] = acc;
    }
    return;
  }
  const int bh = B >> 4, kt = B & 15;
  const int s0 = kt * 64;
  const float* qg = qkv + (size_t)bh * 192 * 1024;
  u16* img = tiles + (size_t)B * 8192;          // 16 KiB per (bh,kt)
  // K half: thread -> (s = tid&63, g = tid>>6), 16 d's, d-strided loads.
  {
    const int s = tid & 63, g = tid >> 6;
    const float* kb = qg + (size_t)(64 + g * 16) * 1024 + s0 + s;
    float kf[16];
#pragma unroll
    for (int i = 0; i < 16; ++i) kf[i] = kb[(size_t)i * 1024];
    u32 kp[8];
#pragma unroll
    for (int j2 = 0; j2 < 8; ++j2) kp[j2] = pkbf(kf[2 * j2], kf[2 * j2 + 1]);
    const int xr = (s & 7) << 3;
    *(uint4*)&img[s * 64 + ((g * 16)     ^ xr)] = make_uint4(kp[0], kp[1], kp[2], kp[3]);
    *(uint4*)&img[s * 64 + ((g * 16 + 8) ^ xr)] = make_uint4(kp[4], kp[5], kp[6], kp[7]);
  }
  // V half: thread -> (dg = tid>>4 : 4 d's, g = tid&15 : 4 consecutive s).
  // col' base for s-group g: cp = ((g>>3)&1)*32 + (g&3)*8 + ((g>>2)&1)*4.
  {
    const int g = tid & 15, dg = tid >> 4;
    const int cp = ((g >> 3) & 1) * 32 + (g & 3) * 8 + ((g >> 2) & 1) * 4;
    const float* vb = qg + (size_t)(128 + dg * 4) * 1024 + s0 + g * 4;
#pragma unroll
    for (int i = 0; i < 4; ++i) {
      f32x4 v = *(const f32x4*)(vb + (size_t)i * 1024);
      const int d = dg * 4 + i;
      *(uint2*)&img[4096 + d * 64 + (cp ^ ((d & 7) << 3))] =
          make_uint2(pkbf(v.x, v.y), pkbf(v.z, v.w));
    }
  }
}

// ---- kernel 2: two-stream flash attention ----------------------------------
__global__ __launch_bounds__(256, 4)
void attn_kernel(const float* __restrict__ qkv, const int* __restrict__ seg,
                 const float* __restrict__ tok, const u16* __restrict__ tiles,
                 float* __restrict__ out) {
  // [buf0 16KB | buf1 16KB] = 32768 B -> 4-5 blocks/CU.
  __shared__ __align__(16) u16 smem[16384];

  const int L  = blockIdx.x;
  const int bh = (L & 7) * 8 + ((L >> 3) & 7);   // same bh -> same XCD residue
  const int qt = L >> 6;                          // 0..15
  const int b  = bh >> 3;
  const int tid = threadIdx.x, wave = tid >> 6, lane = tid & 63;
  const int quad = lane >> 4, l16 = lane & 15;

  const float* qg   = qkv + (size_t)bh * 192 * 1024;
  const int*   segb = seg + b * 1024;
  const u16*   tbh  = tiles + (size_t)bh * (16 * 8192);

  // --- per-lane segment info: lane owns query l16 ---------------------------
  const int tq = qt * 64 + wave * 16 + l16;
  const int mycls = segb[tq];
  int sq[4];                                   // classes of epilogue rows
#pragma unroll
  for (int r = 0; r < 4; ++r) sq[r] = segb[qt * 64 + wave * 16 + quad * 4 + r];

  // --- Q fragments (B-layout: n=l16=query, k=d=kc*32+quad*8+j) --------------
  const float* tn = tok + 8 * 192;
  const float* tc = tok + mycls * 192;
  union { u32 w[4]; bf16x8 v; } q0f[2], qbf[2];
#pragma unroll
  for (int kc = 0; kc < 2; ++kc)
#pragma unroll
    for (int jj = 0; jj < 4; ++jj) {
      int d = kc * 32 + quad * 8 + jj * 2;
      float a0 = qg[(size_t)d * 1024 + tq];
      float a1 = qg[(size_t)(d + 1) * 1024 + tq];
      q0f[kc].w[jj] = pkbf((a0 + tn[d]) * QSCALE, (a1 + tn[d + 1]) * QSCALE);
      qbf[kc].w[jj] = pkbf((a0 + tc[d]) * QSCALE, (a1 + tc[d + 1]) * QSCALE);
    }

  f32x4 O0[4], Ob[4];
#pragma unroll
  for (int dt = 0; dt < 4; ++dt) {
    O0[dt] = (f32x4){0.f, 0.f, 0.f, 0.f};
    Ob[dt] = (f32x4){0.f, 0.f, 0.f, 0.f};
  }
  float rs0 = 0.f, rsb = 0.f;                  // denominator of query l16

  // prologue: DMA tile 0 into buf0
  {
    const char* src = (const char*)tbh + tid * 16;
    char* dst = (char*)smem + tid * 16;
#pragma unroll
    for (int i = 0; i < 4; ++i) gload_lds16(src + i * 4096, dst + i * 4096);
  }

  const int xq = (l16 & 7) << 3;   // XOR for all row&7 == l16&7 accesses

  // ---- key-tile loop (16 x 64 keys) ----------------------------------------
#pragma unroll 2
  for (int kt = 0; kt < 16; ++kt) {
    const int s0 = kt * 64;
    __syncthreads();            // drains our DMA (vmcnt 0) + frees other buf
    if (kt + 1 < 16) {          // prefetch next tile across the whole compute
      const char* src = (const char*)tbh + (size_t)(kt + 1) * 16384 + tid * 16;
      char* dst = (char*)smem + ((kt + 1) & 1) * 16384 + tid * 16;
#pragma unroll
      for (int i = 0; i < 4; ++i) gload_lds16(src + i * 4096, dst + i * 4096);
    }
    // classes of the 16 keys this lane holds (s = n4*16 + quad*4 + r)
    int sk[4][4];
#pragma unroll
    for (int n4 = 0; n4 < 4; ++n4) {
      int4 s4 = *(const int4*)&segb[s0 + n4 * 16 + quad * 4];
      sk[n4][0] = s4.x; sk[n4][1] = s4.y; sk[n4][2] = s4.z; sk[n4][3] = s4.w;
    }

    const u16* ktr = smem + (kt & 1) * 8192;   // K image [s][64]
    const u16* vls = ktr + 4096;               // V image [d][64]

    // ---- S^T = K Q^T, both streams (A=K: m=key=n4*16+l16, k=d) ------------
    f32x4 S0t[4], Sbt[4];
#pragma unroll
    for (int n4 = 0; n4 < 4; ++n4) {
      const int srow = n4 * 16 + l16;          // srow&7 == l16&7 -> xq
      f32x4 a0 = {0.f, 0.f, 0.f, 0.f}, ab = {0.f, 0.f, 0.f, 0.f};
#pragma unroll
      for (int kc = 0; kc < 2; ++kc) {
        bf16x8 kfr = *(const bf16x8*)&ktr[srow * 64 + ((kc * 32 + quad * 8) ^ xq)];
        a0 = __builtin_amdgcn_mfma_f32_16x16x32_bf16(kfr, q0f[kc].v, a0, 0, 0, 0);
        ab = __builtin_amdgcn_mfma_f32_16x16x32_bf16(kfr, qbf[kc].v, ab, 0, 0, 0);
      }
      S0t[n4] = a0; Sbt[n4] = ab;
    }

    // ---- no-max softmax, fully in-register --------------------------------
    // lane holds P[key = n4*16+quad*4+r][query = l16]
    float p0[4][4], pb[4][4];
#pragma unroll
    for (int n4 = 0; n4 < 4; ++n4)
#pragma unroll
      for (int r = 0; r < 4; ++r) {
        p0[n4][r] = fexp2(S0t[n4][r]);
        pb[n4][r] = (sk[n4][r] == mycls) ? fexp2(Sbt[n4][r]) : 0.f;
      }
#pragma unroll
    for (int n4 = 0; n4 < 4; ++n4) {
      rs0 += (p0[n4][0] + p0[n4][1]) + (p0[n4][2] + p0[n4][3]);
      rsb += (pb[n4][0] + pb[n4][1]) + (pb[n4][2] + pb[n4][3]);
    }
    // pack A-frags: elem j of pa[kc] is key col' = kc*32+quad*8+j,
    // i.e. (n4 = 2kc + (j>>2), r = j&3) -- static, no cross-lane.
    union { u32 w[4]; bf16x8 v; } pa0[2], pab[2];
#pragma unroll
    for (int kc = 0; kc < 2; ++kc) {
      pa0[kc].w[0] = pkbf(p0[2 * kc][0],     p0[2 * kc][1]);
      pa0[kc].w[1] = pkbf(p0[2 * kc][2],     p0[2 * kc][3]);
      pa0[kc].w[2] = pkbf(p0[2 * kc + 1][0], p0[2 * kc + 1][1]);
      pa0[kc].w[3] = pkbf(p0[2 * kc + 1][2], p0[2 * kc + 1][3]);
      pab[kc].w[0] = pkbf(pb[2 * kc][0],     pb[2 * kc][1]);
      pab[kc].w[1] = pkbf(pb[2 * kc][2],     pb[2 * kc][3]);
      pab[kc].w[2] = pkbf(pb[2 * kc + 1][0], pb[2 * kc + 1][1]);
      pab[kc].w[3] = pkbf(pb[2 * kc + 1][2], pb[2 * kc + 1][3]);
    }

    // ---- O += P V  (A=P in regs, B=V[k=col'][n=d] from LDS) ---------------
#pragma unroll
    for (int kc = 0; kc < 2; ++kc) {
      const int co = (kc * 32 + quad * 8) ^ xq;
#pragma unroll
      for (int dt = 0; dt < 4; ++dt) {
        bf16x8 vfr = *(const bf16x8*)&vls[(dt * 16 + l16) * 64 + co];
        O0[dt] = __builtin_amdgcn_mfma_f32_16x16x32_bf16(pa0[kc].v, vfr, O0[dt], 0, 0, 0);
        Ob[dt] = __builtin_amdgcn_mfma_f32_16x16x32_bf16(pab[kc].v, vfr, Ob[dt], 0, 0, 0);
      }
    }
  }

  // ---- denominators: reduce across quads, then broadcast row r -------------
  rs0 += __shfl_xor(rs0, 16, 64);  rs0 += __shfl_xor(rs0, 32, 64);
  rsb += __shfl_xor(rsb, 16, 64);  rsb += __shfl_xor(rsb, 32, 64);
  float inv0[4], invb[4];
#pragma unroll
  for (int r = 0; r < 4; ++r) {
    float d0 = __shfl(rs0, quad * 4 + r, 16);   // denom of query quad*4+r
    float db = __shfl(rsb, quad * 4 + r, 16);
    inv0[r] = (d0 > 0.f) ? 1.f / d0 : 0.f;
    invb[r] = (db > 0.f) ? 1.f / db : 0.f;
  }

  // ---- epilogue: divide, add analytic v-biases, transpose via LDS, store ---
  __syncthreads();                        // all LDS tile reads done
  float* fbuf = (float*)smem;             // [64 d][65] fp32 (16640 B)
  const float* tvn = tok + 8 * 192 + 128;
#pragma unroll
  for (int dt = 0; dt < 4; ++dt) {
    const int d = dt * 16 + l16;
    const float bn = tvn[d];
#pragma unroll
    for (int r = 0; r < 4; ++r) {
      float bc = tok[sq[r] * 192 + 128 + d];
      float vA = O0[dt][r] * inv0[r] + bn;
      float vB = Ob[dt][r] * invb[r] + bc;
      fbuf[d * 65 + wave * 16 + quad * 4 + r] = 0.5f * (vA + vB);
    }
  }
  __syncthreads();
  {
    // out flat = d*65536 + bh*1024 + t   (stacked (ch, bH, T) row-major)
    const size_t obase = (size_t)bh * 1024 + qt * 64;
    for (int i = tid; i < 4096; i += 256) {
      int d = i >> 6, t = i & 63;
      out[(size_t)d * 65536 + obase + t] = fbuf[d * 65 + t];
    }
  }
}

// ---- host ------------------------------------------------------------------
extern "C" void kernel_launch(void* const* d_in, const int* in_sizes, int n_in,
                              void* d_out, int out_size, void* d_ws, size_t ws_size,
                              hipStream_t stream) {
  (void)in_sizes; (void)n_in; (void)out_size; (void)ws_size;
  const float* qkv   = (const float*)d_in[0];
  const int*   amask = (const int*)d_in[1];
  const float* emb   = (const float*)d_in[2];
  const float* wcls  = (const float*)d_in[3];
  float* tok   = (float*)d_ws;                       // 1728 floats
  u16*   tiles = (u16*)((char*)d_ws + 8192);         // 16 MiB of tile images
  float* out = (float*)d_out;

  hipLaunchKernelGGL(prep_kernel, dim3(1456), dim3(256), 0, stream,
                     qkv, wcls, emb, tok, tiles);
  hipLaunchKernelGGL(attn_kernel, dim3(1024), dim3(256), 0, stream,
                     qkv, amask, tok, tiles, out);
}

// Round 3
// 134.173 us; speedup vs baseline: 1.0980x; 1.0233x over previous
//
#include <hip/hip_runtime.h>
#include <stdint.h>

typedef unsigned short u16;
typedef unsigned int   u32;
typedef __bf16 bf16_t;
typedef bf16_t bf16x8 __attribute__((ext_vector_type(8)));
typedef bf16_t bf16x2 __attribute__((ext_vector_type(2)));
typedef float  f32x2  __attribute__((ext_vector_type(2)));
typedef float  f32x4  __attribute__((ext_vector_type(4)));

// bs=8, H=8 -> bH=64 ; T=1024 ; ch=64 ; classes 0..7, null token idx 8.
// Math: k-bias is row-constant over surviving keys -> drops out of softmax;
// v-bias passes through softmax as exactly +v_bias -> added in epilogue;
// counter==2 -> out = 0.5*(A_null + A_class).  No-max softmax: logits in
// exp2-domain have sigma~1.44 (scale folded into Q), so raw exp2 is safe.
//
// R12: two query-columns per wave (32 q/wave, 128 q/block, grid 512).
// K-frags and V-frags are read from LDS ONCE and feed 4 MFMAs each
// (2 q-cols x 2 streams) -> LDS reads per query halve (the R11 profile
// showed ~24 us of LDS-pipe occupancy from 4 waves reading identical
// frags).  DMA traffic also halves.  VGPR ~200 under launch_bounds(256,2);
// grid 512 = 2 blocks/CU, all 8 q-blocks of a bh co-resident per XCD ->
// tile images stay L2-hot.
#define QSCALE 0.18033688011112042f   /* 0.125 * log2(e) */

__device__ __forceinline__ u32 pkbf(float a, float b) {
  f32x2 x = {a, b};
  bf16x2 y = __builtin_convertvector(x, bf16x2);   // RNE; v_cvt_pk_bf16_f32
  union { bf16x2 v; u32 u; } c; c.v = y; return c.u;
}

__device__ __forceinline__ float fexp2(float x) {
#if __has_builtin(__builtin_amdgcn_exp2f)
  return __builtin_amdgcn_exp2f(x);
#else
  float r;
  asm("v_exp_f32 %0, %1\n\ts_nop 0" : "=v"(r) : "v"(x));
  return r;
#endif
}

// async global->LDS, 16B per lane.  HW dest = wave-uniform base + lane*16.
__device__ __forceinline__ void gload_lds16(const void* g, void* l) {
  __builtin_amdgcn_global_load_lds(
      (const __attribute__((address_space(1))) void*)g,
      (__attribute__((address_space(3))) void*)l, 16, 0, 0);
}

// ---- kernel 1: prep ---------------------------------------------------------
// blocks 0..1023  : (bh,kt) -> 16KB tile image: [K 8KB | V 8KB], bf16,
//                   XOR-swizzled: elem offset ^= (row&7)<<3 within each row.
//                   K rows = key s (64 elems d);  V rows = d (64 cols,
//                   col' = sigma(s) matching the in-register P layout).
// blocks 1024..1455: tok[c][j] = sum_i W_cls[j,i]*embed[c,i].
__global__ __launch_bounds__(256)
void prep_kernel(const float* __restrict__ qkv,
                 const float* __restrict__ W, const float* __restrict__ E,
                 float* __restrict__ tok, u16* __restrict__ tiles) {
  const int B = blockIdx.x;
  const int tid = threadIdx.x;
  if (B >= 1024) {
    const int gw = (B - 1024) * 4 + (tid >> 6);
    const int lane = tid & 63;
    if (gw < 1728) {
      const int c = gw / 192, j = gw - c * 192;
      const f32x4* w4 = (const f32x4*)(W + (size_t)j * 512 + lane * 8);
      const f32x4* e4 = (const f32x4*)(E + (size_t)c * 512 + lane * 8);
      float acc = 0.f;
#pragma unroll
      for (int i = 0; i < 2; ++i) {
        f32x4 w = w4[i], e = e4[i];
        acc += w.x * e.x + w.y * e.y + w.z * e.z + w.w * e.w;
      }
#pragma unroll
      for (int off = 32; off; off >>= 1) acc += __shfl_xor(acc, off, 64);
      if (lane == 0) tok[c * 192 + j] = acc;
    }
    return;
  }
  const int bh = B >> 4, kt = B & 15;
  const int s0 = kt * 64;
  const float* qg = qkv + (size_t)bh * 192 * 1024;
  u16* img = tiles + (size_t)B * 8192;          // 16 KiB per (bh,kt)
  // K half: thread -> (s = tid&63, g = tid>>6), 16 d's, d-strided loads.
  {
    const int s = tid & 63, g = tid >> 6;
    const float* kb = qg + (size_t)(64 + g * 16) * 1024 + s0 + s;
    float kf[16];
#pragma unroll
    for (int i = 0; i < 16; ++i) kf[i] = kb[(size_t)i * 1024];
    u32 kp[8];
#pragma unroll
    for (int j2 = 0; j2 < 8; ++j2) kp[j2] = pkbf(kf[2 * j2], kf[2 * j2 + 1]);
    const int xr = (s & 7) << 3;
    *(uint4*)&img[s * 64 + ((g * 16)     ^ xr)] = make_uint4(kp[0], kp[1], kp[2], kp[3]);
    *(uint4*)&img[s * 64 + ((g * 16 + 8) ^ xr)] = make_uint4(kp[4], kp[5], kp[6], kp[7]);
  }
  // V half: thread -> (dg = tid>>4 : 4 d's, g = tid&15 : 4 consecutive s).
  // col' base for s-group g: cp = ((g>>3)&1)*32 + (g&3)*8 + ((g>>2)&1)*4.
  {
    const int g = tid & 15, dg = tid >> 4;
    const int cp = ((g >> 3) & 1) * 32 + (g & 3) * 8 + ((g >> 2) & 1) * 4;
    const float* vb = qg + (size_t)(128 + dg * 4) * 1024 + s0 + g * 4;
#pragma unroll
    for (int i = 0; i < 4; ++i) {
      f32x4 v = *(const f32x4*)(vb + (size_t)i * 1024);
      const int d = dg * 4 + i;
      *(uint2*)&img[4096 + d * 64 + (cp ^ ((d & 7) << 3))] =
          make_uint2(pkbf(v.x, v.y), pkbf(v.z, v.w));
    }
  }
}

// ---- kernel 2: two-stream, two-qcol flash attention ------------------------
__global__ __launch_bounds__(256, 2)
void attn_kernel(const float* __restrict__ qkv, const int* __restrict__ seg,
                 const float* __restrict__ tok, const u16* __restrict__ tiles,
                 float* __restrict__ out) {
  // tiles: [buf0 16KB | buf1 16KB] = 32768 B; epilogue fbuf 64x132 f32 =
  // 33792 B -> alloc max = 33792 B (2 blocks/CU fine).
  __shared__ __align__(16) u16 smem[16896];

  const int L  = blockIdx.x;                     // 0..511
  const int bh = (L & 7) * 8 + ((L >> 3) & 7);   // same bh -> same XCD residue
  const int qb = L >> 6;                          // 0..7 (128-query block)
  const int b  = bh >> 3;
  const int tid = threadIdx.x, wave = tid >> 6, lane = tid & 63;
  const int quad = lane >> 4, l16 = lane & 15;

  const float* qg   = qkv + (size_t)bh * 192 * 1024;
  const int*   segb = seg + b * 1024;
  const u16*   tbh  = tiles + (size_t)bh * (16 * 8192);

  // --- per-lane query info: lane owns queries tqA (col A) and tqB (col B) ---
  const int q0i = qb * 128 + wave * 32;
  const int tqA = q0i + l16, tqB = tqA + 16;
  const int mycA = segb[tqA], mycB = segb[tqB];
  int sqA[4], sqB[4];                  // classes of epilogue rows
#pragma unroll
  for (int r = 0; r < 4; ++r) {
    sqA[r] = segb[q0i + quad * 4 + r];
    sqB[r] = segb[q0i + 16 + quad * 4 + r];
  }

  // --- Q fragments (B-layout: n=l16=query, k=d=kc*32+quad*8+j) --------------
  const float* tn  = tok + 8 * 192;
  const float* tcA = tok + mycA * 192;
  const float* tcB = tok + mycB * 192;
  union { u32 w[4]; bf16x8 v; } qA0[2], qAb[2], qB0[2], qBb[2];
#pragma unroll
  for (int kc = 0; kc < 2; ++kc)
#pragma unroll
    for (int jj = 0; jj < 4; ++jj) {
      int d = kc * 32 + quad * 8 + jj * 2;
      float a0 = qg[(size_t)d * 1024 + tqA];
      float a1 = qg[(size_t)(d + 1) * 1024 + tqA];
      float b0 = qg[(size_t)d * 1024 + tqB];
      float b1 = qg[(size_t)(d + 1) * 1024 + tqB];
      qA0[kc].w[jj] = pkbf((a0 + tn[d])  * QSCALE, (a1 + tn[d + 1])  * QSCALE);
      qAb[kc].w[jj] = pkbf((a0 + tcA[d]) * QSCALE, (a1 + tcA[d + 1]) * QSCALE);
      qB0[kc].w[jj] = pkbf((b0 + tn[d])  * QSCALE, (b1 + tn[d + 1])  * QSCALE);
      qBb[kc].w[jj] = pkbf((b0 + tcB[d]) * QSCALE, (b1 + tcB[d + 1]) * QSCALE);
    }

  f32x4 OA0[4], OAb[4], OB0[4], OBb[4];
#pragma unroll
  for (int dt = 0; dt < 4; ++dt) {
    OA0[dt] = (f32x4){0.f, 0.f, 0.f, 0.f};  OAb[dt] = (f32x4){0.f, 0.f, 0.f, 0.f};
    OB0[dt] = (f32x4){0.f, 0.f, 0.f, 0.f};  OBb[dt] = (f32x4){0.f, 0.f, 0.f, 0.f};
  }
  float rsA0 = 0.f, rsAb = 0.f, rsB0 = 0.f, rsBb = 0.f;

  // prologue: DMA tile 0 into buf0
  {
    const char* src = (const char*)tbh + tid * 16;
    char* dst = (char*)smem + tid * 16;
#pragma unroll
    for (int i = 0; i < 4; ++i) gload_lds16(src + i * 4096, dst + i * 4096);
  }

  const int xq = (l16 & 7) << 3;   // XOR for all row&7 == l16&7 accesses

  // ---- key-tile loop (16 x 64 keys) ----------------------------------------
#pragma unroll 2
  for (int kt = 0; kt < 16; ++kt) {
    const int s0 = kt * 64;
    __syncthreads();            // drains our DMA (vmcnt 0) + frees other buf
    if (kt + 1 < 16) {          // prefetch next tile across the whole compute
      const char* src = (const char*)tbh + (size_t)(kt + 1) * 16384 + tid * 16;
      char* dst = (char*)smem + ((kt + 1) & 1) * 16384 + tid * 16;
#pragma unroll
      for (int i = 0; i < 4; ++i) gload_lds16(src + i * 4096, dst + i * 4096);
    }
    // classes of the 16 keys this lane holds (s = n4*16 + quad*4 + r)
    int sk[4][4];
#pragma unroll
    for (int n4 = 0; n4 < 4; ++n4) {
      int4 s4 = *(const int4*)&segb[s0 + n4 * 16 + quad * 4];
      sk[n4][0] = s4.x; sk[n4][1] = s4.y; sk[n4][2] = s4.z; sk[n4][3] = s4.w;
    }

    const u16* ktr = smem + (kt & 1) * 8192;   // K image [s][64]
    const u16* vls = ktr + 4096;               // V image [d][64]

    // ---- S^T = K Q^T, two q-cols x two streams; K-frag read ONCE ----------
    f32x4 SA0[4], SAb[4], SB0[4], SBb[4];
#pragma unroll
    for (int n4 = 0; n4 < 4; ++n4) {
      const int srow = n4 * 16 + l16;          // srow&7 == l16&7 -> xq
      f32x4 a0 = {0.f, 0.f, 0.f, 0.f}, ab = {0.f, 0.f, 0.f, 0.f};
      f32x4 c0 = {0.f, 0.f, 0.f, 0.f}, cb = {0.f, 0.f, 0.f, 0.f};
#pragma unroll
      for (int kc = 0; kc < 2; ++kc) {
        bf16x8 kfr = *(const bf16x8*)&ktr[srow * 64 + ((kc * 32 + quad * 8) ^ xq)];
        a0 = __builtin_amdgcn_mfma_f32_16x16x32_bf16(kfr, qA0[kc].v, a0, 0, 0, 0);
        ab = __builtin_amdgcn_mfma_f32_16x16x32_bf16(kfr, qAb[kc].v, ab, 0, 0, 0);
        c0 = __builtin_amdgcn_mfma_f32_16x16x32_bf16(kfr, qB0[kc].v, c0, 0, 0, 0);
        cb = __builtin_amdgcn_mfma_f32_16x16x32_bf16(kfr, qBb[kc].v, cb, 0, 0, 0);
      }
      SA0[n4] = a0; SAb[n4] = ab; SB0[n4] = c0; SBb[n4] = cb;
    }

    // ---- no-max softmax, fully in-register, per q-col ---------------------
    // lane holds P[key = n4*16+quad*4+r][query = l16 of the column]
    union { u32 w[4]; bf16x8 v; } paA0[2], paAb[2], paB0[2], paBb[2];
#define SOFTMAX_PACK(S0, Sb, myc, rs0, rsb, pa0, pab)                          \
    {                                                                          \
      float p0[4][4], pb[4][4];                                                \
      _Pragma("unroll")                                                        \
      for (int n4 = 0; n4 < 4; ++n4)                                           \
        _Pragma("unroll")                                                      \
        for (int r = 0; r < 4; ++r) {                                          \
          p0[n4][r] = fexp2(S0[n4][r]);                                        \
          pb[n4][r] = (sk[n4][r] == myc) ? fexp2(Sb[n4][r]) : 0.f;             \
        }                                                                      \
      _Pragma("unroll")                                                        \
      for (int n4 = 0; n4 < 4; ++n4) {                                         \
        rs0 += (p0[n4][0] + p0[n4][1]) + (p0[n4][2] + p0[n4][3]);              \
        rsb += (pb[n4][0] + pb[n4][1]) + (pb[n4][2] + pb[n4][3]);              \
      }                                                                        \
      _Pragma("unroll")                                                        \
      for (int kc = 0; kc < 2; ++kc) {                                         \
        pa0[kc].w[0] = pkbf(p0[2 * kc][0],     p0[2 * kc][1]);                 \
        pa0[kc].w[1] = pkbf(p0[2 * kc][2],     p0[2 * kc][3]);                 \
        pa0[kc].w[2] = pkbf(p0[2 * kc + 1][0], p0[2 * kc + 1][1]);             \
        pa0[kc].w[3] = pkbf(p0[2 * kc + 1][2], p0[2 * kc + 1][3]);             \
        pab[kc].w[0] = pkbf(pb[2 * kc][0],     pb[2 * kc][1]);                 \
        pab[kc].w[1] = pkbf(pb[2 * kc][2],     pb[2 * kc][3]);                 \
        pab[kc].w[2] = pkbf(pb[2 * kc + 1][0], pb[2 * kc + 1][1]);             \
        pab[kc].w[3] = pkbf(pb[2 * kc + 1][2], pb[2 * kc + 1][3]);             \
      }                                                                        \
    }
    SOFTMAX_PACK(SA0, SAb, mycA, rsA0, rsAb, paA0, paAb)
    SOFTMAX_PACK(SB0, SBb, mycB, rsB0, rsBb, paB0, paBb)
#undef SOFTMAX_PACK

    // ---- O += P V ; V-frag read ONCE feeds 4 MFMAs ------------------------
#pragma unroll
    for (int kc = 0; kc < 2; ++kc) {
      const int co = (kc * 32 + quad * 8) ^ xq;
#pragma unroll
      for (int dt = 0; dt < 4; ++dt) {
        bf16x8 vfr = *(const bf16x8*)&vls[(dt * 16 + l16) * 64 + co];
        OA0[dt] = __builtin_amdgcn_mfma_f32_16x16x32_bf16(paA0[kc].v, vfr, OA0[dt], 0, 0, 0);
        OAb[dt] = __builtin_amdgcn_mfma_f32_16x16x32_bf16(paAb[kc].v, vfr, OAb[dt], 0, 0, 0);
        OB0[dt] = __builtin_amdgcn_mfma_f32_16x16x32_bf16(paB0[kc].v, vfr, OB0[dt], 0, 0, 0);
        OBb[dt] = __builtin_amdgcn_mfma_f32_16x16x32_bf16(paBb[kc].v, vfr, OBb[dt], 0, 0, 0);
      }
    }
  }

  // ---- denominators: reduce across quads, then broadcast rows --------------
  rsA0 += __shfl_xor(rsA0, 16, 64);  rsA0 += __shfl_xor(rsA0, 32, 64);
  rsAb += __shfl_xor(rsAb, 16, 64);  rsAb += __shfl_xor(rsAb, 32, 64);
  rsB0 += __shfl_xor(rsB0, 16, 64);  rsB0 += __shfl_xor(rsB0, 32, 64);
  rsBb += __shfl_xor(rsBb, 16, 64);  rsBb += __shfl_xor(rsBb, 32, 64);
  float invA0[4], invAb[4], invB0[4], invBb[4];
#pragma unroll
  for (int r = 0; r < 4; ++r) {
    float a0 = __shfl(rsA0, quad * 4 + r, 16);
    float ab = __shfl(rsAb, quad * 4 + r, 16);
    float b0 = __shfl(rsB0, quad * 4 + r, 16);
    float bb = __shfl(rsBb, quad * 4 + r, 16);
    invA0[r] = (a0 > 0.f) ? 1.f / a0 : 0.f;
    invAb[r] = (ab > 0.f) ? 1.f / ab : 0.f;
    invB0[r] = (b0 > 0.f) ? 1.f / b0 : 0.f;
    invBb[r] = (bb > 0.f) ? 1.f / bb : 0.f;
  }

  // ---- epilogue: divide, add analytic v-biases, transpose via LDS, store ---
  __syncthreads();                        // all LDS tile reads done
  float* fbuf = (float*)smem;             // [64 d][132] fp32 (33792 B)
  const float* tvn = tok + 8 * 192 + 128;
#pragma unroll
  for (int dt = 0; dt < 4; ++dt) {
    const int d = dt * 16 + l16;
    const float bn = tvn[d];
    f32x4 wA, wB;
#pragma unroll
    for (int r = 0; r < 4; ++r) {
      float bcA = tok[sqA[r] * 192 + 128 + d];
      float bcB = tok[sqB[r] * 192 + 128 + d];
      wA[r] = 0.5f * (OA0[dt][r] * invA0[r] + bn + OAb[dt][r] * invAb[r] + bcA);
      wB[r] = 0.5f * (OB0[dt][r] * invB0[r] + bn + OBb[dt][r] * invBb[r] + bcB);
    }
    *(f32x4*)&fbuf[d * 132 + wave * 32 + quad * 4]      = wA;
    *(f32x4*)&fbuf[d * 132 + wave * 32 + 16 + quad * 4] = wB;
  }
  __syncthreads();
  {
    // out flat = d*65536 + bh*1024 + t   (stacked (ch, bH, T) row-major)
    const size_t obase = (size_t)bh * 1024 + qb * 128;
    for (int i = tid; i < 8192; i += 256) {
      int d = i >> 7, t = i & 127;
      out[(size_t)d * 65536 + obase + t] = fbuf[d * 132 + t];
    }
  }
}

// ---- host ------------------------------------------------------------------
extern "C" void kernel_launch(void* const* d_in, const int* in_sizes, int n_in,
                              void* d_out, int out_size, void* d_ws, size_t ws_size,
                              hipStream_t stream) {
  (void)in_sizes; (void)n_in; (void)out_size; (void)ws_size;
  const float* qkv   = (const float*)d_in[0];
  const int*   amask = (const int*)d_in[1];
  const float* emb   = (const float*)d_in[2];
  const float* wcls  = (const float*)d_in[3];
  float* tok   = (float*)d_ws;                       // 1728 floats
  u16*   tiles = (u16*)((char*)d_ws + 8192);         // 16 MiB of tile images
  float* out = (float*)d_out;

  hipLaunchKernelGGL(prep_kernel, dim3(1456), dim3(256), 0, stream,
                     qkv, wcls, emb, tok, tiles);
  hipLaunchKernelGGL(attn_kernel, dim3(512), dim3(256), 0, stream,
                     qkv, amask, tok, tiles, out);
}